// Round 1
// 430.142 us; speedup vs baseline: 1.2078x; 1.2078x over previous
//
#include <hip/hip_runtime.h>

namespace {
constexpr int V = 50000;
constexpr int E = 640000;
constexpr int HALF = 320000;
constexpr int NREL2 = 474;
constexpr int C = 128;
constexpr int NCHUNK = (V + 255) / 256; // 196
}

typedef _Float16 h4 __attribute__((ext_vector_type(4)));
typedef _Float16 h8 __attribute__((ext_vector_type(8)));

// ---------------- precompute: c[k,i], b[k,i], Min[k,i,o], Mout[k,i,o] -------
__global__ void prep_kernel(const float* __restrict__ nrw, const float* __restrict__ nw,
                            const float* __restrict__ inw, const float* __restrict__ outw,
                            const float* __restrict__ aw,
                            float* __restrict__ cbuf, float* __restrict__ bbuf,
                            float* __restrict__ Min, float* __restrict__ Mout) {
  int tid = blockIdx.x * 256 + threadIdx.x;
  if (tid < 512) {
    int k = tid >> 7, i = tid & 127;
    float acc = 0.f;
    for (int d = 0; d < 32; ++d) acc += nrw[k*4096 + i*32 + d] * aw[d];
    cbuf[tid] = acc;
  } else if (tid < 1024) {
    int u = tid - 512; int k = u >> 7, i = u & 127;
    float acc = 0.f;
    for (int d = 0; d < 32; ++d) acc += nw[k*4096 + i*32 + d] * aw[32 + d];
    bbuf[u] = acc;
  } else if (tid < 1024 + 16384) {
    int u = tid - 1024; int k = u >> 12, rem = u & 4095, i = rem >> 5, o = rem & 31;
    float acc = 0.f;
    for (int d = 0; d < 32; ++d) acc += nrw[k*4096 + i*32 + d] * inw[k*1024 + d*32 + o];
    Min[u] = acc;
  } else if (tid < 1024 + 32768) {
    int u = tid - 1024 - 16384; int k = u >> 12, rem = u & 4095, i = rem >> 5, o = rem & 31;
    float acc = 0.f;
    for (int d = 0; d < 32; ++d) acc += nrw[k*4096 + i*32 + d] * outw[k*1024 + d*32 + o];
    Mout[u] = acc;
  }
}

// ---------------- q[t,k] = node_repr[t] . b_k  (16 lanes per node) ----------
// Cooperative: 16 consecutive lanes read one node row as a contiguous 512B
// segment (16B/lane), partial-dot 8 channels each, butterfly-reduce.
__global__ __launch_bounds__(256) void qnode_kernel(const float* __restrict__ nrp,
                                                    const float* __restrict__ bbuf,
                                                    float* __restrict__ qbuf) {
  const int t = blockIdx.x * 16 + (threadIdx.x >> 4);
  const int l = threadIdx.x & 15;
  if (t >= V) return;
  const float* row = nrp + (size_t)t * C + l * 8;
  float4 a0 = *(const float4*)(row);
  float4 a1 = *(const float4*)(row + 4);
  float p[4];
#pragma unroll
  for (int k = 0; k < 4; ++k) {
    const float* brow = bbuf + k * C + l * 8;
    float4 b0 = *(const float4*)(brow);
    float4 b1 = *(const float4*)(brow + 4);
    p[k] = a0.x * b0.x + a0.y * b0.y + a0.z * b0.z + a0.w * b0.w
         + a1.x * b1.x + a1.y * b1.y + a1.z * b1.z + a1.w * b1.w;
  }
#pragma unroll
  for (int m = 1; m < 16; m <<= 1) {
#pragma unroll
    for (int k = 0; k < 4; ++k) p[k] += __shfl_xor(p[k], m);
  }
  if (l == 0) *(float4*)(qbuf + 4 * (size_t)t) = make_float4(p[0], p[1], p[2], p[3]);
}

// ---------------- CSR build -------------------------------------------------
__global__ void hist_kernel(const int* __restrict__ dst, int* __restrict__ cnt) {
  int e = blockIdx.x * 256 + threadIdx.x;
  if (e < E) atomicAdd(&cnt[dst[e]], 1);
}

__global__ void scan_sum_kernel(const int* __restrict__ cnt, int* __restrict__ bsum) {
  __shared__ int sd[256];
  int tid = threadIdx.x;
  int idx = blockIdx.x * 256 + tid;
  int v = (idx < V) ? cnt[idx] : 0;
  sd[tid] = v; __syncthreads();
  for (int s = 128; s > 0; s >>= 1) {
    if (tid < s) sd[tid] += sd[tid + s];
    __syncthreads();
  }
  if (tid == 0) bsum[blockIdx.x] = sd[0];
}

__global__ void scan_top_kernel(int* __restrict__ bsum) {
  __shared__ int sd[256];
  int tid = threadIdx.x;
  int v = (tid < NCHUNK) ? bsum[tid] : 0;
  sd[tid] = v; __syncthreads();
  for (int ofs = 1; ofs < 256; ofs <<= 1) {
    int t = (tid >= ofs) ? sd[tid - ofs] : 0;
    __syncthreads();
    sd[tid] += t;
    __syncthreads();
  }
  if (tid < NCHUNK) bsum[tid] = sd[tid] - v;  // exclusive
}

__global__ void scan_apply_kernel(const int* __restrict__ cnt, const int* __restrict__ bsum,
                                  int* __restrict__ off) {
  __shared__ int sd[256];
  int tid = threadIdx.x;
  int idx = blockIdx.x * 256 + tid;
  int v = (idx < V) ? cnt[idx] : 0;
  sd[tid] = v; __syncthreads();
  for (int ofs = 1; ofs < 256; ofs <<= 1) {
    int t = (tid >= ofs) ? sd[tid - ofs] : 0;
    __syncthreads();
    sd[tid] += t;
    __syncthreads();
  }
  if (idx < V) off[idx] = bsum[blockIdx.x] + sd[tid] - v;  // exclusive
}

// sort edge metadata by dst: pack src | etype<<16 | dir<<25 ; gather norm, dst
__global__ void place_kernel(const int* __restrict__ dst, const int* __restrict__ src,
                             const int* __restrict__ etype, const float* __restrict__ norm,
                             const int* __restrict__ off, int* __restrict__ cur,
                             int* __restrict__ metas, float* __restrict__ norms_s,
                             int* __restrict__ dsts_s) {
  int e = blockIdx.x * 256 + threadIdx.x;
  if (e < E) {
    int t = dst[e];
    int pos = off[t] + atomicAdd(&cur[t], 1);
    metas[pos] = src[e] | (etype[e] << 16) | ((e >= HALF) ? (1 << 25) : 0);
    norms_s[pos] = norm[e];
    dsts_s[pos] = t;
  }
}

// ---------------- phase A: per-edge attention weights (+ optional fp16 x) ---
// Cooperative: 16 lanes per edge. Node/rel rows are read as contiguous 512B
// segments (16B/lane), xs written as a contiguous 256B segment per edge
// (full cache lines -> no write-allocate RMW). The 4 attention dots finish
// with a 4-step shfl_xor butterfly within the 16-lane group.
template <bool WRITE_XS>
__global__ __launch_bounds__(256) void attw_kernel(
    const float* __restrict__ nrp, const float* __restrict__ rel,
    const int* __restrict__ metas, const float* __restrict__ norms_s,
    const int* __restrict__ dsts_s, const float* __restrict__ qbuf,
    const float* __restrict__ cbuf, float* __restrict__ wbuf,
    _Float16* __restrict__ xs) {
  const int i = blockIdx.x * 16 + (threadIdx.x >> 4);  // edge
  const int l = threadIdx.x & 15;                      // 8-channel chunk
  if (i >= E) return;
  const int meta = metas[i];
  const int s = meta & 0xFFFF;
  const int r = (meta >> 16) & 0x1FF;
  const float* arow = nrp + (size_t)s * C + l * 8;
  const float* brow = rel + (size_t)r * C + l * 8;
  float4 a0 = *(const float4*)(arow);
  float4 a1 = *(const float4*)(arow + 4);
  float4 b0 = *(const float4*)(brow);
  float4 b1 = *(const float4*)(brow + 4);
  float x0 = a0.x * b0.x, x1 = a0.y * b0.y, x2 = a0.z * b0.z, x3 = a0.w * b0.w;
  float x4 = a1.x * b1.x, x5 = a1.y * b1.y, x6 = a1.z * b1.z, x7 = a1.w * b1.w;
  if (WRITE_XS) {
    h8 o;
    o[0] = (_Float16)x0; o[1] = (_Float16)x1; o[2] = (_Float16)x2; o[3] = (_Float16)x3;
    o[4] = (_Float16)x4; o[5] = (_Float16)x5; o[6] = (_Float16)x6; o[7] = (_Float16)x7;
    *(h8*)(xs + (size_t)i * C + l * 8) = o;
  }
  float p[4];
#pragma unroll
  for (int k = 0; k < 4; ++k) {
    const float* crow = cbuf + k * C + l * 8;
    float4 c0 = *(const float4*)(crow);
    float4 c1 = *(const float4*)(crow + 4);
    p[k] = x0 * c0.x + x1 * c0.y + x2 * c0.z + x3 * c0.w
         + x4 * c1.x + x5 * c1.y + x6 * c1.z + x7 * c1.w;
  }
#pragma unroll
  for (int m = 1; m < 16; m <<= 1) {
#pragma unroll
    for (int k = 0; k < 4; ++k) p[k] += __shfl_xor(p[k], m);
  }
  const float nr = norms_s[i];
  const int d = dsts_s[i];
  float4 q4 = *(const float4*)(qbuf + 4 * (size_t)d);
  float l0 = fmaxf(p[0] + q4.x, 0.f);
  float l1 = fmaxf(p[1] + q4.y, 0.f);
  float l2 = fmaxf(p[2] + q4.z, 0.f);
  float l3 = fmaxf(p[3] + q4.w, 0.f);
  float mx = fmaxf(fmaxf(l0, l1), fmaxf(l2, l3));
  float e0 = __expf(l0 - mx), e1 = __expf(l1 - mx);
  float e2 = __expf(l2 - mx), e3 = __expf(l3 - mx);
  float inv = nr / (e0 + e1 + e2 + e3);
  float4 wv = make_float4(e0 * inv, e1 * inv, e2 * inv, e3 * inv);
  if (WRITE_XS && (meta & (1 << 25))) {
    wv.x = -wv.x; wv.y = -wv.y; wv.z = -wv.z; wv.w = -wv.w;  // dir in sign
  }
  if (l == 0) *(float4*)(wbuf + 4 * (size_t)i) = wv;
}

// ---------------- phase B (streaming): z accum from linear xs + contraction -
// wave = node; 2 groups of 32 lanes alternate edges; batch 8 pairs in flight.
// Contraction: thread=(dir,k,o) streams its coalesced M panel; z from LDS.
__global__ __launch_bounds__(256) void zacc_stream_kernel(
    const _Float16* __restrict__ xs, const float* __restrict__ wbuf,
    const int* __restrict__ cnt, const int* __restrict__ off,
    const float* __restrict__ Min, const float* __restrict__ Mout,
    float* __restrict__ h) {
  __shared__ float zli[4][4][132];
  __shared__ float zlo[4][4][132];
  __shared__ float red[4][4][32];
  const int w = threadIdx.x >> 6;
  const int lane = threadIdx.x & 63;
  const int g = lane >> 5;
  const int l32 = lane & 31;
  const int t = blockIdx.x * 4 + w;
  const int ch = l32 * 4;

  float4 zi[4], zo[4];
#pragma unroll
  for (int k = 0; k < 4; ++k) {
    zi[k] = make_float4(0.f, 0.f, 0.f, 0.f);
    zo[k] = make_float4(0.f, 0.f, 0.f, 0.f);
  }

  const int start = off[t];
  const int deg = cnt[t];

  for (int base = 0; base < deg; base += 16) {
    h4 xv[8];
    float4 wv[8];
#pragma unroll
    for (int u = 0; u < 8; ++u) {
      int idx = base + 2 * u + g;
      bool valid = idx < deg;
      int e = start + min(idx, deg - 1);
      xv[u] = ((const h4*)xs)[(size_t)e * 32 + l32];
      float4 t4 = ((const float4*)wbuf)[e];
      wv[u].x = valid ? t4.x : 0.f;
      wv[u].y = valid ? t4.y : 0.f;
      wv[u].z = valid ? t4.z : 0.f;
      wv[u].w = valid ? t4.w : 0.f;
    }
#pragma unroll
    for (int u = 0; u < 8; ++u) {
      float x0 = (float)xv[u].x, x1 = (float)xv[u].y;
      float x2 = (float)xv[u].z, x3 = (float)xv[u].w;
      unsigned int sgn = __float_as_uint(wv[u].x) >> 31;  // 1 => out-dir
      float fin = sgn ? 0.f : 1.f;
      float fout = 1.f - fin;
      float a0 = fabsf(wv[u].x), a1 = fabsf(wv[u].y);
      float a2 = fabsf(wv[u].z), a3 = fabsf(wv[u].w);
      float wi0 = a0 * fin, wo0 = a0 * fout;
      float wi1 = a1 * fin, wo1 = a1 * fout;
      float wi2 = a2 * fin, wo2 = a2 * fout;
      float wi3 = a3 * fin, wo3 = a3 * fout;
      zi[0].x += wi0 * x0; zi[0].y += wi0 * x1; zi[0].z += wi0 * x2; zi[0].w += wi0 * x3;
      zi[1].x += wi1 * x0; zi[1].y += wi1 * x1; zi[1].z += wi1 * x2; zi[1].w += wi1 * x3;
      zi[2].x += wi2 * x0; zi[2].y += wi2 * x1; zi[2].z += wi2 * x2; zi[2].w += wi2 * x3;
      zi[3].x += wi3 * x0; zi[3].y += wi3 * x1; zi[3].z += wi3 * x2; zi[3].w += wi3 * x3;
      zo[0].x += wo0 * x0; zo[0].y += wo0 * x1; zo[0].z += wo0 * x2; zo[0].w += wo0 * x3;
      zo[1].x += wo1 * x0; zo[1].y += wo1 * x1; zo[1].z += wo1 * x2; zo[1].w += wo1 * x3;
      zo[2].x += wo2 * x0; zo[2].y += wo2 * x1; zo[2].z += wo2 * x2; zo[2].w += wo2 * x3;
      zo[3].x += wo3 * x0; zo[3].y += wo3 * x1; zo[3].z += wo3 * x2; zo[3].w += wo3 * x3;
    }
  }

  // combine the two 32-lane groups, park z in LDS
#pragma unroll
  for (int k = 0; k < 4; ++k) {
    zi[k].x += __shfl_xor(zi[k].x, 32);
    zi[k].y += __shfl_xor(zi[k].y, 32);
    zi[k].z += __shfl_xor(zi[k].z, 32);
    zi[k].w += __shfl_xor(zi[k].w, 32);
    zo[k].x += __shfl_xor(zo[k].x, 32);
    zo[k].y += __shfl_xor(zo[k].y, 32);
    zo[k].z += __shfl_xor(zo[k].z, 32);
    zo[k].w += __shfl_xor(zo[k].w, 32);
  }
  if (g == 0) {
#pragma unroll
    for (int k = 0; k < 4; ++k) *(float4*)(&zli[w][k][ch]) = zi[k];
  } else {
#pragma unroll
    for (int k = 0; k < 4; ++k) *(float4*)(&zlo[w][k][ch]) = zo[k];
  }
  __syncthreads();

  // contraction: thread = (dir, k, o); M panel reads coalesced, z via LDS bcast
  const int tid = threadIdx.x;
  const int dir = tid >> 7;
  const int kk = (tid >> 5) & 3;
  const int o = tid & 31;
  const float* Mp = (dir ? Mout : Min) + kk * 4096 + o;
  const float* zbase = dir ? &zlo[0][0][0] : &zli[0][0][0];
  float acc0 = 0.f, acc1 = 0.f, acc2 = 0.f, acc3 = 0.f;
#pragma unroll 4
  for (int i = 0; i < 128; ++i) {
    float m = Mp[i * 32];
    acc0 += zbase[0 * 528 + kk * 132 + i] * m;
    acc1 += zbase[1 * 528 + kk * 132 + i] * m;
    acc2 += zbase[2 * 528 + kk * 132 + i] * m;
    acc3 += zbase[3 * 528 + kk * 132 + i] * m;
  }
  if (dir) {
    red[0][kk][o] = acc0;
    red[1][kk][o] = acc1;
    red[2][kk][o] = acc2;
    red[3][kk][o] = acc3;
  }
  __syncthreads();
  if (!dir) {
    const float third = 1.f / 3.f;
    h[(size_t)(blockIdx.x * 4 + 0) * C + kk * 32 + o] = (acc0 + red[0][kk][o]) * third;
    h[(size_t)(blockIdx.x * 4 + 1) * C + kk * 32 + o] = (acc1 + red[1][kk][o]) * third;
    h[(size_t)(blockIdx.x * 4 + 2) * C + kk * 32 + o] = (acc2 + red[2][kk][o]) * third;
    h[(size_t)(blockIdx.x * 4 + 3) * C + kk * 32 + o] = (acc3 + red[3][kk][o]) * third;
  }
}

// ---------------- phase B (fallback, round-4): gather + accum + contraction -
__global__ __launch_bounds__(256) void main2_kernel(
    const float* __restrict__ nrp, const float* __restrict__ rel,
    const int* __restrict__ cnt, const int* __restrict__ off,
    const int* __restrict__ metas, const float* __restrict__ wbuf,
    const float* __restrict__ Min, const float* __restrict__ Mout,
    float* __restrict__ h) {
  __shared__ float zli[4][4][132];
  __shared__ float zlo[4][4][132];
  const int w = threadIdx.x >> 6;
  const int lane = threadIdx.x & 63;
  const int g = lane >> 5;
  const int t = blockIdx.x * 4 + w;
  const int ch = (lane & 31) * 4;

  float4 zi[4], zo[4];
#pragma unroll
  for (int k = 0; k < 4; ++k) {
    zi[k] = make_float4(0.f, 0.f, 0.f, 0.f);
    zo[k] = make_float4(0.f, 0.f, 0.f, 0.f);
  }

  const int start = off[t];
  const int deg = cnt[t];

  for (int base = 0; base < deg; base += 64) {
    const int cn = min(64, deg - base);
    int m_l = 0;
    if (lane < cn) m_l = metas[start + base + lane];
    const int nj = (cn + 1) >> 1;
    int idx0 = min(g, cn - 1);
    bool v0 = (g < cn);
    int mc = __shfl(m_l, idx0);
    float4 wc = *(const float4*)(wbuf + 4 * (size_t)(start + base + idx0));
    if (!v0) { wc.x = 0.f; wc.y = 0.f; wc.z = 0.f; wc.w = 0.f; }
    float4 ac = *(const float4*)(nrp + (size_t)(mc & 0xFFFF) * C + ch);
    float4 bc = *(const float4*)(rel + (size_t)((mc >> 16) & 0x1FF) * C + ch);
    for (int j = 0; j < nj; ++j) {
      int idx1 = 2 * (j + 1) + g;
      bool v1 = (idx1 < cn);
      idx1 = min(idx1, cn - 1);
      int m1 = __shfl(m_l, idx1);
      float4 w1 = *(const float4*)(wbuf + 4 * (size_t)(start + base + idx1));
      if (!v1) { w1.x = 0.f; w1.y = 0.f; w1.z = 0.f; w1.w = 0.f; }
      float4 a1 = *(const float4*)(nrp + (size_t)(m1 & 0xFFFF) * C + ch);
      float4 b1 = *(const float4*)(rel + (size_t)((m1 >> 16) & 0x1FF) * C + ch);

      float4 x;
      x.x = ac.x * bc.x; x.y = ac.y * bc.y; x.z = ac.z * bc.z; x.w = ac.w * bc.w;
      float sif = (mc & (1 << 25)) ? 0.f : 1.f;  // 0 => out-edge
      float wi0 = wc.x * sif, wo0 = wc.x - wi0;
      float wi1 = wc.y * sif, wo1 = wc.y - wi1;
      float wi2 = wc.z * sif, wo2 = wc.z - wi2;
      float wi3 = wc.w * sif, wo3 = wc.w - wi3;
      zi[0].x += wi0 * x.x; zi[0].y += wi0 * x.y; zi[0].z += wi0 * x.z; zi[0].w += wi0 * x.w;
      zi[1].x += wi1 * x.x; zi[1].y += wi1 * x.y; zi[1].z += wi1 * x.z; zi[1].w += wi1 * x.w;
      zi[2].x += wi2 * x.x; zi[2].y += wi2 * x.y; zi[2].z += wi2 * x.z; zi[2].w += wi2 * x.w;
      zi[3].x += wi3 * x.x; zi[3].y += wi3 * x.y; zi[3].z += wi3 * x.z; zi[3].w += wi3 * x.w;
      zo[0].x += wo0 * x.x; zo[0].y += wo0 * x.y; zo[0].z += wo0 * x.z; zo[0].w += wo0 * x.w;
      zo[1].x += wo1 * x.x; zo[1].y += wo1 * x.y; zo[1].z += wo1 * x.z; zo[1].w += wo1 * x.w;
      zo[2].x += wo2 * x.x; zo[2].y += wo2 * x.y; zo[2].z += wo2 * x.z; zo[2].w += wo2 * x.w;
      zo[3].x += wo3 * x.x; zo[3].y += wo3 * x.y; zo[3].z += wo3 * x.z; zo[3].w += wo3 * x.w;
      mc = m1; wc = w1; ac = a1; bc = b1;
    }
  }

#pragma unroll
  for (int k = 0; k < 4; ++k) {
    zi[k].x += __shfl_xor(zi[k].x, 32);
    zi[k].y += __shfl_xor(zi[k].y, 32);
    zi[k].z += __shfl_xor(zi[k].z, 32);
    zi[k].w += __shfl_xor(zi[k].w, 32);
    zo[k].x += __shfl_xor(zo[k].x, 32);
    zo[k].y += __shfl_xor(zo[k].y, 32);
    zo[k].z += __shfl_xor(zo[k].z, 32);
    zo[k].w += __shfl_xor(zo[k].w, 32);
  }
  if (g == 0) {
#pragma unroll
    for (int k = 0; k < 4; ++k) *(float4*)(&zli[w][k][ch]) = zi[k];
  } else {
#pragma unroll
    for (int k = 0; k < 4; ++k) *(float4*)(&zlo[w][k][ch]) = zo[k];
  }
  __syncthreads();

  const int kk = lane >> 4;
  const int o0 = (lane & 15) * 2;
  const float* Mi = Min + kk * 4096 + o0;
  const float* Mo = Mout + kk * 4096 + o0;
  float acc0 = 0.f, acc1 = 0.f;
  for (int i = 0; i < C; ++i) {
    float a_ = zli[w][kk][i];
    float b_ = zlo[w][kk][i];
    float2 mi = *(const float2*)(Mi + i * 32);
    float2 mo = *(const float2*)(Mo + i * 32);
    acc0 += a_ * mi.x + b_ * mo.x;
    acc1 += a_ * mi.y + b_ * mo.y;
  }
  const float third = 1.f / 3.f;
  h[(size_t)t * C + kk * 32 + o0] = acc0 * third;
  h[(size_t)t * C + kk * 32 + o0 + 1] = acc1 * third;
}

// ---------------- self-loop + bias + BN partial stats -----------------------
__global__ __launch_bounds__(256) void selfloop_kernel(
    float* __restrict__ h, const float* __restrict__ lr,
    const float* __restrict__ lw, const float* __restrict__ bias,
    float* __restrict__ bnsum, float* __restrict__ bnsq) {
  __shared__ float lwl[16384];      // 64 KB: lw[i][j]
  __shared__ float xr[4][8][128];   // 16 KB
  __shared__ float red[256];
  const int tid = threadIdx.x;
  const int w = tid >> 6, lane = tid & 63;
  for (int i = tid; i < 16384; i += 256) lwl[i] = lw[i];
  __syncthreads();

  const int c0 = 2 * lane, c1 = c0 + 1;
  const float lr0 = lr[c0], lr1 = lr[c1];
  const float bv0 = bias[c0], bv1 = bias[c1];
  float s0 = 0.f, s1 = 0.f, sq0 = 0.f, sq1 = 0.f;

  const int wg = blockIdx.x * 4 + w;
  const int nw = gridDim.x * 4;
  for (int rb = wg * 8; rb < V; rb += nw * 8) {
    const int nrows = min(8, V - rb);
    float2 hv[8];
#pragma unroll
    for (int rr = 0; rr < 8; ++rr) {
      if (rr < nrows) {
        hv[rr] = *(const float2*)(h + (size_t)(rb + rr) * C + c0);
      } else {
        hv[rr] = make_float2(0.f, 0.f);
      }
      xr[w][rr][c0] = hv[rr].x * lr0;
      xr[w][rr][c1] = hv[rr].y * lr1;
    }
    float acc[8][2] = {};
    for (int i = 0; i < C; ++i) {
      float2 lwv = *(const float2*)(&lwl[i * C + c0]);
#pragma unroll
      for (int rr = 0; rr < 8; ++rr) {
        float xv = xr[w][rr][i];
        acc[rr][0] += xv * lwv.x;
        acc[rr][1] += xv * lwv.y;
      }
    }
    const float third = 1.f / 3.f;
#pragma unroll
    for (int rr = 0; rr < 8; ++rr) {
      if (rr < nrows) {
        float h0 = hv[rr].x + acc[rr][0] * third + bv0;
        float h1 = hv[rr].y + acc[rr][1] * third + bv1;
        *(float2*)(h + (size_t)(rb + rr) * C + c0) = make_float2(h0, h1);
        s0 += h0; s1 += h1; sq0 += h0 * h0; sq1 += h1 * h1;
      }
    }
  }

  __syncthreads();
  red[tid] = s0; __syncthreads();
  if (tid < 64) {
    float v = red[tid] + red[tid + 64] + red[tid + 128] + red[tid + 192];
    atomicAdd(&bnsum[2 * tid], v);
  }
  __syncthreads();
  red[tid] = s1; __syncthreads();
  if (tid < 64) {
    float v = red[tid] + red[tid + 64] + red[tid + 128] + red[tid + 192];
    atomicAdd(&bnsum[2 * tid + 1], v);
  }
  __syncthreads();
  red[tid] = sq0; __syncthreads();
  if (tid < 64) {
    float v = red[tid] + red[tid + 64] + red[tid + 128] + red[tid + 192];
    atomicAdd(&bnsq[2 * tid], v);
  }
  __syncthreads();
  red[tid] = sq1; __syncthreads();
  if (tid < 64) {
    float v = red[tid] + red[tid + 64] + red[tid + 128] + red[tid + 192];
    atomicAdd(&bnsq[2 * tid + 1], v);
  }
}

// ---------------- BN finalize + tanh (fused) --------------------------------
__global__ void tanh_kernel(float* __restrict__ h,
                            const float* __restrict__ bnsum, const float* __restrict__ bnsq,
                            const float* __restrict__ gamma, const float* __restrict__ beta) {
  int idx = blockIdx.x * 256 + threadIdx.x;
  int base = idx * 4;
  if (base >= V * C) return;
  int j = base & 127;
  const float invV = 1.f / (float)V;
  float4 v = *(float4*)(h + base);
  float o[4] = {v.x, v.y, v.z, v.w};
#pragma unroll
  for (int cidx = 0; cidx < 4; ++cidx) {
    float mean = bnsum[j + cidx] * invV;
    float var = bnsq[j + cidx] * invV - mean * mean;
    float sc = gamma[j + cidx] * rsqrtf(var + 1e-5f);
    float sh = beta[j + cidx] - sc * mean;
    o[cidx] = tanhf(sc * o[cidx] + sh);
  }
  v.x = o[0]; v.y = o[1]; v.z = o[2]; v.w = o[3];
  *(float4*)(h + base) = v;
}

// ---------------- rel_out = rel_repr @ w_rel --------------------------------
__global__ __launch_bounds__(128) void relout_kernel(
    const float* __restrict__ rel, const float* __restrict__ wrel,
    float* __restrict__ out) {
  __shared__ float rr[128];
  int tid = threadIdx.x;
  int row = blockIdx.x;
  rr[tid] = rel[row * C + tid];
  __syncthreads();
  float acc = 0.f;
#pragma unroll 4
  for (int i = 0; i < C; ++i) acc += rr[i] * wrel[i * C + tid];
  out[row * C + tid] = acc;
}

extern "C" void kernel_launch(void* const* d_in, const int* in_sizes, int n_in,
                              void* d_out, int out_size, void* d_ws, size_t ws_size,
                              hipStream_t stream) {
  const float* node_repr  = (const float*)d_in[0];
  const float* rel_repr   = (const float*)d_in[1];
  const int*   src        = (const int*)d_in[2];
  const int*   dst        = (const int*)d_in[3];
  const int*   etype      = (const int*)d_in[4];
  const float* norm       = (const float*)d_in[5];
  const float* node_w     = (const float*)d_in[6];
  const float* node_rel_w = (const float*)d_in[7];
  const float* in_w       = (const float*)d_in[8];
  const float* out_w      = (const float*)d_in[9];
  const float* att_w      = (const float*)d_in[10];
  const float* loop_rel   = (const float*)d_in[11];
  const float* loop_w     = (const float*)d_in[12];
  const float* w_rel      = (const float*)d_in[13];
  const float* bias       = (const float*)d_in[14];
  const float* bn_gamma   = (const float*)d_in[15];
  const float* bn_beta    = (const float*)d_in[16];

  float* out = (float*)d_out;
  float* h = out;                       // [V,128] accumulator, finalized in place
  float* rel_out = out + (size_t)V * C; // [474,128]

  // workspace layout (all float4/h4 users stay 16B-aligned)
  int* cnt = (int*)d_ws;                // V
  int* cur = cnt + V;                   // V
  float* bnsum = (float*)(cur + V);     // 128
  float* bnsq = bnsum + 128;            // 128  -- zero region ends (2V+256)
  int* off = (int*)(bnsq + 128);        // V
  int* metas = off + V;                 // E
  float* norms_s = (float*)(metas + E); // E
  int* dsts_s = (int*)(norms_s + E);    // E
  float* wbuf = (float*)(dsts_s + E);   // 4E
  int* bsum = (int*)(wbuf + 4 * (size_t)E); // 256
  float* qbuf = (float*)(bsum + 256);   // 4V
  float* cbuf = qbuf + 4 * V;           // 512
  float* bbuf = cbuf + 512;             // 512
  float* Min = bbuf + 512;              // 16384
  float* Mout = Min + 16384;            // 16384
  _Float16* xs = (_Float16*)(Mout + 16384); // E*128 halves (streaming path only)

  const size_t base_bytes = (size_t)((char*)xs - (char*)d_ws);
  const size_t need_bytes = base_bytes + (size_t)E * C * sizeof(_Float16);
  const bool streaming = (ws_size >= need_bytes);

  hipMemsetAsync(cnt, 0, (size_t)(2 * V + 256) * 4, stream);

  prep_kernel<<<(1024 + 32768 + 255) / 256, 256, 0, stream>>>(
      node_rel_w, node_w, in_w, out_w, att_w, cbuf, bbuf, Min, Mout);
  qnode_kernel<<<(V + 15) / 16, 256, 0, stream>>>(node_repr, bbuf, qbuf);
  hist_kernel<<<E / 256, 256, 0, stream>>>(dst, cnt);
  scan_sum_kernel<<<NCHUNK, 256, 0, stream>>>(cnt, bsum);
  scan_top_kernel<<<1, 256, 0, stream>>>(bsum);
  scan_apply_kernel<<<NCHUNK, 256, 0, stream>>>(cnt, bsum, off);
  place_kernel<<<E / 256, 256, 0, stream>>>(dst, src, etype, norm, off, cur,
                                            metas, norms_s, dsts_s);
  if (streaming) {
    attw_kernel<true><<<E / 16, 256, 0, stream>>>(node_repr, rel_repr, metas,
                                                  norms_s, dsts_s, qbuf, cbuf,
                                                  wbuf, xs);
    zacc_stream_kernel<<<V / 4, 256, 0, stream>>>(xs, wbuf, cnt, off, Min, Mout, h);
  } else {
    attw_kernel<false><<<E / 16, 256, 0, stream>>>(node_repr, rel_repr, metas,
                                                   norms_s, dsts_s, qbuf, cbuf,
                                                   wbuf, nullptr);
    main2_kernel<<<V / 4, 256, 0, stream>>>(node_repr, rel_repr, cnt, off, metas,
                                            wbuf, Min, Mout, h);
  }
  selfloop_kernel<<<1024, 256, 0, stream>>>(h, loop_rel, loop_w, bias, bnsum, bnsq);
  tanh_kernel<<<(V * C / 4 + 255) / 256, 256, 0, stream>>>(h, bnsum, bnsq, bn_gamma, bn_beta);
  relout_kernel<<<NREL2, 128, 0, stream>>>(rel_repr, w_rel, rel_out);
}